// Round 3
// baseline (456.679 us; speedup 1.0000x reference)
//
#include <hip/hip_runtime.h>
#include <hip/hip_bf16.h>

typedef __hip_bfloat16 bf16;

#define NGRAPH 128

// ---------------- degree histogram ----------------
__global__ __launch_bounds__(256) void deg_kernel(const int* __restrict__ ei,
                                                  int* __restrict__ deg, int E, int N) {
    int e = blockIdx.x * 256 + threadIdx.x;
    if (e < E) {
        int d = ei[E + e];                 // dst = ei[1][e]
        d = max(0, min(d, N - 1));         // defensive clamp
        atomicAdd(&deg[d], 1);
    }
}

// ---------------- 3-kernel exclusive scan over deg[N] ----------------
__global__ __launch_bounds__(256) void scan1_kernel(const int* __restrict__ deg,
                                                    int* __restrict__ bsum, int N) {
    __shared__ int tmp[256];
    int i = blockIdx.x * 256 + threadIdx.x;
    tmp[threadIdx.x] = (i < N) ? deg[i] : 0;
    __syncthreads();
    for (int off = 128; off > 0; off >>= 1) {
        if (threadIdx.x < off) tmp[threadIdx.x] += tmp[threadIdx.x + off];
        __syncthreads();
    }
    if (threadIdx.x == 0) bsum[blockIdx.x] = tmp[0];
}

__global__ void scan2_kernel(const int* __restrict__ bsum, int* __restrict__ boff, int nb) {
    if (threadIdx.x == 0 && blockIdx.x == 0) {
        int acc = 0;
        for (int b = 0; b < nb; ++b) { boff[b] = acc; acc += bsum[b]; }
    }
}

__global__ __launch_bounds__(256) void scan3_kernel(const int* __restrict__ deg,
                                                    const int* __restrict__ boff,
                                                    int* __restrict__ row_start,
                                                    float* __restrict__ dinv, int N) {
    __shared__ int tmp[256];
    int i = blockIdx.x * 256 + threadIdx.x;
    int v = (i < N) ? deg[i] : 0;
    tmp[threadIdx.x] = v;
    __syncthreads();
    for (int off = 1; off < 256; off <<= 1) {
        int t = (threadIdx.x >= off) ? tmp[threadIdx.x - off] : 0;
        __syncthreads();
        tmp[threadIdx.x] += t;
        __syncthreads();
    }
    if (i < N) {
        int excl = tmp[threadIdx.x] - v;
        int rs = boff[blockIdx.x] + excl;
        row_start[i] = rs;
        if (i == N - 1) row_start[N] = rs + v;
        dinv[i] = rsqrtf((float)(v + 1));   // +1 self loop
    }
}

// ---------------- CSR fill (dst-sorted src list) ----------------
__global__ __launch_bounds__(256) void fill_kernel(const int* __restrict__ ei,
                                                   const int* __restrict__ row_start,
                                                   int* __restrict__ cursor,
                                                   int* __restrict__ csr_src, int E, int N) {
    int e = blockIdx.x * 256 + threadIdx.x;
    if (e < E) {
        int s = ei[e];     s = max(0, min(s, N - 1));
        int d = ei[E + e]; d = max(0, min(d, N - 1));
        int pos = row_start[d] + atomicAdd(&cursor[d], 1);
        if (pos >= 0 && pos < E) csr_src[pos] = s;
    }
}

// ---------------- P = (A @ W) * dinv[row] -> bf16,  A: Nx64 f32, W: 64x64 f32 ----------------
__global__ __launch_bounds__(256) void mm64_kernel(const float* __restrict__ A,
                                                   const float* __restrict__ W,
                                                   const float* __restrict__ dinv,
                                                   bf16* __restrict__ P, int N) {
    __shared__ float Wl[64 * 64];
    __shared__ float Al[4 * 64];
    int tid = threadIdx.x;
    for (int i = tid; i < 4096; i += 256) Wl[i] = W[i];
    int r = tid >> 6, c = tid & 63;
    int row = blockIdx.x * 4 + r;
    if (row < N) Al[tid] = A[row * 64 + c];
    __syncthreads();
    if (row >= N) return;
    float acc = 0.f;
#pragma unroll
    for (int k = 0; k < 64; ++k) acc += Al[r * 64 + k] * Wl[k * 64 + c];
    P[row * 64 + c] = __float2bfloat16(acc * dinv[row]);
}

// ---------------- aggregate: out[n] = act(dinv[n]*(P[n] + sum P[src]) + b) ----------------
__global__ __launch_bounds__(256) void agg_kernel(const bf16* __restrict__ P,
                                                  const int* __restrict__ row_start,
                                                  const int* __restrict__ csr_src,
                                                  const float* __restrict__ dinv,
                                                  const float* __restrict__ bias,
                                                  float* __restrict__ outf,
                                                  int N, int do_relu) {
    int wave = threadIdx.x >> 6;
    int lane = threadIdx.x & 63;
    int node = blockIdx.x * 4 + wave;
    if (node >= N) return;
    float acc = __bfloat162float(P[node * 64 + lane]);   // self-loop term
    int beg = row_start[node], end = row_start[node + 1];
    for (int i = beg; i < end; i += 64) {
        int e = i + lane;
        int s = (e < end) ? csr_src[e] : 0;
        int m = min(end - i, 64);
        for (int j = 0; j < m; ++j) {
            int sj = __shfl(s, j);
            acc += __bfloat162float(P[sj * 64 + lane]);
        }
    }
    float r = acc * dinv[node] + bias[lane];
    if (do_relu) r = fmaxf(r, 0.f);
    outf[node * 64 + lane] = r;
}

// ---------------- global mean pool (batch sorted ascending) ----------------
__device__ __forceinline__ int lower_bound_dev(const int* a, int n, int key) {
    int lo = 0, hi = n;
    while (lo < hi) {
        int mid = (lo + hi) >> 1;
        if (a[mid] < key) lo = mid + 1; else hi = mid;
    }
    return lo;
}

__global__ __launch_bounds__(64) void pool_kernel(const float* __restrict__ h2,
                                                  const int* __restrict__ batch,
                                                  float* __restrict__ out_reps, int N) {
    int g = blockIdx.x;
    int f = threadIdx.x;
    int lo = lower_bound_dev(batch, N, g);
    int hi = lower_bound_dev(batch, N, g + 1);
    float acc = 0.f;
    for (int r = lo; r < hi; ++r) acc += h2[r * 64 + f];
    float cnt = (float)(hi - lo);
    out_reps[g * 64 + f] = acc / fmaxf(cnt, 1.f);
}

// ---------------- classifier head ----------------
__global__ __launch_bounds__(64) void head_kernel(const float* __restrict__ reps,
                                                  const float* __restrict__ Wc1,
                                                  const float* __restrict__ bc1,
                                                  const float* __restrict__ Wc2,
                                                  const float* __restrict__ bc2,
                                                  float* __restrict__ out) {
    __shared__ float rep[64];
    __shared__ float t[64];
    int g = blockIdx.x;
    int tid = threadIdx.x;
    rep[tid] = reps[g * 64 + tid];
    __syncthreads();
    float acc = bc1[tid];
#pragma unroll
    for (int k = 0; k < 64; ++k) acc += rep[k] * Wc1[k * 64 + tid];
    t[tid] = fmaxf(acc, 0.f);
    __syncthreads();
    if (tid < 16) {
        float a2 = bc2[tid];
#pragma unroll
        for (int k = 0; k < 64; ++k) a2 += t[k] * Wc2[k * 16 + tid];
        out[g * 16 + tid] = a2;
    }
}

extern "C" void kernel_launch(void* const* d_in, const int* in_sizes, int n_in,
                              void* d_out, int out_size, void* d_ws, size_t ws_size,
                              hipStream_t stream) {
    const float* x    = (const float*)d_in[0];
    const int*   ei   = (const int*)d_in[1];
    const int*   batch= (const int*)d_in[2];
    const float* W1   = (const float*)d_in[3];
    const float* b1   = (const float*)d_in[4];
    const float* W2   = (const float*)d_in[5];
    const float* b2   = (const float*)d_in[6];
    const float* Wc1  = (const float*)d_in[7];
    const float* bc1  = (const float*)d_in[8];
    const float* Wc2  = (const float*)d_in[9];
    const float* bc2  = (const float*)d_in[10];

    const int N = in_sizes[2];          // 50000
    const int E = in_sizes[1] / 2;      // 800000

    // ---- compact workspace layout (~10.4 MB) ----
    char* ws = (char*)d_ws;
    size_t off = 0;
    auto alloc = [&](size_t bytes) { void* p = ws + off; off += (bytes + 255) & ~(size_t)255; return p; };
    int*   deg       = (int*)  alloc((size_t)N * 4);
    int*   cursor    = (int*)  alloc((size_t)N * 4);
    size_t zero_bytes = off;                       // deg + cursor must start at 0
    float* dinv      = (float*)alloc((size_t)N * 4);
    int*   row_start = (int*)  alloc((size_t)(N + 1) * 4);
    int*   bsum      = (int*)  alloc(1024);
    int*   boff      = (int*)  alloc(1024);
    int*   csr_src   = (int*)  alloc((size_t)E * 4);
    bf16*  P         = (bf16*) alloc((size_t)N * 64 * 2);   // scaled projection, bf16
    (void)ws_size; (void)n_in; (void)out_size;

    float* out_h      = (float*)d_out;                      // [N,64] f32 (also h1 buffer)
    float* out_reps   = out_h + (size_t)N * 64;             // [128,64] f32
    float* out_logits = out_reps + (size_t)NGRAPH * 64;     // [128,16] f32

    int nbE = (E + 255) / 256;
    int nbN = (N + 255) / 256;
    int nb4 = (N + 3) / 4;

    hipMemsetAsync(d_ws, 0, zero_bytes, stream);
    deg_kernel<<<nbE, 256, 0, stream>>>(ei, deg, E, N);
    scan1_kernel<<<nbN, 256, 0, stream>>>(deg, bsum, N);
    scan2_kernel<<<1, 64, 0, stream>>>(bsum, boff, nbN);
    scan3_kernel<<<nbN, 256, 0, stream>>>(deg, boff, row_start, dinv, N);
    fill_kernel<<<nbE, 256, 0, stream>>>(ei, row_start, cursor, csr_src, E, N);

    // layer 1: P = (x@W1)*dinv ; h1 = relu(dinv*(P[n]+sum)+b1)  -> d_out h-region (f32)
    mm64_kernel<<<nb4, 256, 0, stream>>>(x, W1, dinv, P, N);
    agg_kernel<<<nb4, 256, 0, stream>>>(P, row_start, csr_src, dinv, b1, out_h, N, 1);

    // layer 2: P = (h1@W2)*dinv ; h2 = dinv*(P[n]+sum)+b2 -> overwrites d_out h-region
    mm64_kernel<<<nb4, 256, 0, stream>>>(out_h, W2, dinv, P, N);
    agg_kernel<<<nb4, 256, 0, stream>>>(P, row_start, csr_src, dinv, b2, out_h, N, 0);

    // pooling + head
    pool_kernel<<<NGRAPH, 64, 0, stream>>>(out_h, batch, out_reps, N);
    head_kernel<<<NGRAPH, 64, 0, stream>>>(out_reps, Wc1, bc1, Wc2, bc2, out_logits);
}

// Round 4
// 401.215 us; speedup vs baseline: 1.1382x; 1.1382x over previous
//
#include <hip/hip_runtime.h>
#include <hip/hip_bf16.h>

typedef __hip_bfloat16 bf16;

#define NGRAPH 128

// ---------------- degree histogram ----------------
__global__ __launch_bounds__(256) void deg_kernel(const int* __restrict__ ei,
                                                  int* __restrict__ deg, int E, int N) {
    int e = blockIdx.x * 256 + threadIdx.x;
    if (e < E) {
        int d = ei[E + e];                 // dst = ei[1][e]
        d = max(0, min(d, N - 1));
        atomicAdd(&deg[d], 1);
    }
}

// ---------------- scan: per-block sums ----------------
__global__ __launch_bounds__(256) void scan1_kernel(const int* __restrict__ deg,
                                                    int* __restrict__ bsum, int N) {
    __shared__ int tmp[256];
    int i = blockIdx.x * 256 + threadIdx.x;
    tmp[threadIdx.x] = (i < N) ? deg[i] : 0;
    __syncthreads();
    for (int off = 128; off > 0; off >>= 1) {
        if (threadIdx.x < off) tmp[threadIdx.x] += tmp[threadIdx.x + off];
        __syncthreads();
    }
    if (threadIdx.x == 0) bsum[blockIdx.x] = tmp[0];
}

// ---------------- scan: exclusive scan of block sums (parallel, chunked) ----------------
__global__ __launch_bounds__(256) void scan2_kernel(const int* __restrict__ bsum,
                                                    int* __restrict__ boff, int nb) {
    __shared__ int tmp[256];
    __shared__ int carry;
    int tid = threadIdx.x;
    if (tid == 0) carry = 0;
    __syncthreads();
    for (int base = 0; base < nb; base += 256) {
        int i = base + tid;
        int v = (i < nb) ? bsum[i] : 0;
        tmp[tid] = v;
        __syncthreads();
        for (int off = 1; off < 256; off <<= 1) {
            int t = (tid >= off) ? tmp[tid - off] : 0;
            __syncthreads();
            tmp[tid] += t;
            __syncthreads();
        }
        if (i < nb) boff[i] = carry + tmp[tid] - v;
        __syncthreads();
        if (tid == 0) carry += tmp[255];
        __syncthreads();
    }
}

// ---------------- scan: per-element row_start + dinv ----------------
__global__ __launch_bounds__(256) void scan3_kernel(const int* __restrict__ deg,
                                                    const int* __restrict__ boff,
                                                    int* __restrict__ row_start,
                                                    float* __restrict__ dinv, int N) {
    __shared__ int tmp[256];
    int i = blockIdx.x * 256 + threadIdx.x;
    int v = (i < N) ? deg[i] : 0;
    tmp[threadIdx.x] = v;
    __syncthreads();
    for (int off = 1; off < 256; off <<= 1) {
        int t = (threadIdx.x >= off) ? tmp[threadIdx.x - off] : 0;
        __syncthreads();
        tmp[threadIdx.x] += t;
        __syncthreads();
    }
    if (i < N) {
        int excl = tmp[threadIdx.x] - v;
        int rs = boff[blockIdx.x] + excl;
        row_start[i] = rs;
        if (i == N - 1) row_start[N] = rs + v;
        dinv[i] = rsqrtf((float)(v + 1));   // +1 self loop
    }
}

// ---------------- CSR fill (dst-sorted src list) ----------------
__global__ __launch_bounds__(256) void fill_kernel(const int* __restrict__ ei,
                                                   const int* __restrict__ row_start,
                                                   int* __restrict__ cursor,
                                                   int* __restrict__ csr_src, int E, int N) {
    int e = blockIdx.x * 256 + threadIdx.x;
    if (e < E) {
        int s = ei[e];     s = max(0, min(s, N - 1));
        int d = ei[E + e]; d = max(0, min(d, N - 1));
        int pos = row_start[d] + atomicAdd(&cursor[d], 1);
        if (pos >= 0 && pos < E) csr_src[pos] = s;
    }
}

// ---------------- P1 = (x @ W1) * dinv  (wave-per-node, grid-stride) ----------------
__global__ __launch_bounds__(256) void proj_kernel(const float* __restrict__ A,
                                                   const float* __restrict__ W,
                                                   const float* __restrict__ dinv,
                                                   bf16* __restrict__ P, int N) {
    __shared__ float Wl[4096];
    for (int i = threadIdx.x; i < 4096; i += 256) Wl[i] = W[i];
    __syncthreads();
    int lane = threadIdx.x & 63;
    int wid = (blockIdx.x * 256 + threadIdx.x) >> 6;
    int nwaves = (gridDim.x * 256) >> 6;
    for (int node = wid; node < N; node += nwaves) {
        float a = A[(size_t)node * 64 + lane];
        float acc = 0.f;
#pragma unroll
        for (int k = 0; k < 64; ++k) acc += __shfl(a, k) * Wl[k * 64 + lane];
        P[(size_t)node * 64 + lane] = __float2bfloat16(acc * dinv[node]);
    }
}

// ---- layer1 aggregate + fused layer2 projection:
//      h1 = relu(dinv*(P1[n]+sum P1[src])+b1);  P2[n] = (h1@W2)*dinv  ----
__global__ __launch_bounds__(256) void agg_proj_kernel(const bf16* __restrict__ P1,
                                                       const int* __restrict__ row_start,
                                                       const int* __restrict__ csr_src,
                                                       const float* __restrict__ dinv,
                                                       const float* __restrict__ b1,
                                                       const float* __restrict__ W2,
                                                       bf16* __restrict__ P2, int N) {
    __shared__ float Wl[4096];
    for (int i = threadIdx.x; i < 4096; i += 256) Wl[i] = W2[i];
    __syncthreads();
    int lane = threadIdx.x & 63;
    int wid = (blockIdx.x * 256 + threadIdx.x) >> 6;
    int nwaves = (gridDim.x * 256) >> 6;
    for (int node = wid; node < N; node += nwaves) {
        float acc = __bfloat162float(P1[(size_t)node * 64 + lane]);   // self-loop
        int beg = row_start[node], end = row_start[node + 1];
        for (int i = beg; i < end; i += 64) {
            int e = i + lane;
            int s = (e < end) ? csr_src[e] : 0;
            int m = min(end - i, 64);
            for (int j = 0; j < m; ++j) {
                int sj = __shfl(s, j);
                acc += __bfloat162float(P1[(size_t)sj * 64 + lane]);
            }
        }
        float h1 = fmaxf(acc * dinv[node] + b1[lane], 0.f);
        float acc2 = 0.f;
#pragma unroll
        for (int k = 0; k < 64; ++k) acc2 += __shfl(h1, k) * Wl[k * 64 + lane];
        P2[(size_t)node * 64 + lane] = __float2bfloat16(acc2 * dinv[node]);
    }
}

// ---- layer2 aggregate + fused mean-pool accumulation ----
__global__ __launch_bounds__(256) void agg_pool_kernel(const bf16* __restrict__ P2,
                                                       const int* __restrict__ row_start,
                                                       const int* __restrict__ csr_src,
                                                       const float* __restrict__ dinv,
                                                       const float* __restrict__ b2,
                                                       const int* __restrict__ batch,
                                                       float* __restrict__ out_h,
                                                       float* __restrict__ accum, int N) {
    int lane = threadIdx.x & 63;
    int wid = (blockIdx.x * 256 + threadIdx.x) >> 6;
    int nwaves = (gridDim.x * 256) >> 6;
    for (int node = wid; node < N; node += nwaves) {
        float acc = __bfloat162float(P2[(size_t)node * 64 + lane]);   // self-loop
        int beg = row_start[node], end = row_start[node + 1];
        for (int i = beg; i < end; i += 64) {
            int e = i + lane;
            int s = (e < end) ? csr_src[e] : 0;
            int m = min(end - i, 64);
            for (int j = 0; j < m; ++j) {
                int sj = __shfl(s, j);
                acc += __bfloat162float(P2[(size_t)sj * 64 + lane]);
            }
        }
        float h2 = acc * dinv[node] + b2[lane];
        out_h[(size_t)node * 64 + lane] = h2;
        int g = batch[node];
        g = max(0, min(g, NGRAPH - 1));
        atomicAdd(&accum[g * 64 + lane], h2);
    }
}

// ---------------- finalize pool (divide by count) + classifier head ----------------
__device__ __forceinline__ int lower_bound_dev(const int* a, int n, int key) {
    int lo = 0, hi = n;
    while (lo < hi) {
        int mid = (lo + hi) >> 1;
        if (a[mid] < key) lo = mid + 1; else hi = mid;
    }
    return lo;
}

__global__ __launch_bounds__(64) void final_kernel(const float* __restrict__ accum,
                                                   const int* __restrict__ batch,
                                                   const float* __restrict__ Wc1,
                                                   const float* __restrict__ bc1,
                                                   const float* __restrict__ Wc2,
                                                   const float* __restrict__ bc2,
                                                   float* __restrict__ out_reps,
                                                   float* __restrict__ out_logits, int N) {
    __shared__ float rep[64];
    __shared__ float t[64];
    int g = blockIdx.x;
    int f = threadIdx.x;
    int lo = lower_bound_dev(batch, N, g);
    int hi = lower_bound_dev(batch, N, g + 1);
    float cnt = (float)(hi - lo);
    float r = accum[g * 64 + f] / fmaxf(cnt, 1.f);
    out_reps[g * 64 + f] = r;
    rep[f] = r;
    __syncthreads();
    float acc = bc1[f];
#pragma unroll
    for (int k = 0; k < 64; ++k) acc += rep[k] * Wc1[k * 64 + f];
    t[f] = fmaxf(acc, 0.f);
    __syncthreads();
    if (f < 16) {
        float a2 = bc2[f];
#pragma unroll
        for (int k = 0; k < 64; ++k) a2 += t[k] * Wc2[k * 16 + f];
        out_logits[g * 16 + f] = a2;
    }
}

extern "C" void kernel_launch(void* const* d_in, const int* in_sizes, int n_in,
                              void* d_out, int out_size, void* d_ws, size_t ws_size,
                              hipStream_t stream) {
    const float* x    = (const float*)d_in[0];
    const int*   ei   = (const int*)d_in[1];
    const int*   batch= (const int*)d_in[2];
    const float* W1   = (const float*)d_in[3];
    const float* b1   = (const float*)d_in[4];
    const float* W2   = (const float*)d_in[5];
    const float* b2   = (const float*)d_in[6];
    const float* Wc1  = (const float*)d_in[7];
    const float* bc1  = (const float*)d_in[8];
    const float* Wc2  = (const float*)d_in[9];
    const float* bc2  = (const float*)d_in[10];

    const int N = in_sizes[2];          // 50000
    const int E = in_sizes[1] / 2;      // 800000

    // ---- workspace layout (~7.3 MB) ----
    char* ws = (char*)d_ws;
    size_t off = 0;
    auto alloc = [&](size_t bytes) { void* p = ws + off; off += (bytes + 255) & ~(size_t)255; return p; };
    int*   deg       = (int*)  alloc((size_t)N * 4);
    int*   cursor    = (int*)  alloc((size_t)N * 4);
    float* accum     = (float*)alloc((size_t)NGRAPH * 64 * 4);
    size_t zero_bytes = off;                       // deg + cursor + accum start at 0
    float* dinv      = (float*)alloc((size_t)N * 4);
    int*   row_start = (int*)  alloc((size_t)(N + 1) * 4);
    int*   bsum      = (int*)  alloc(1024);
    int*   boff      = (int*)  alloc(1024);
    int*   csr_src   = (int*)  alloc((size_t)E * 4);
    bf16*  P1        = (bf16*) alloc((size_t)N * 64 * 2);
    bf16*  P2        = (bf16*) alloc((size_t)N * 64 * 2);
    (void)ws_size; (void)n_in; (void)out_size;

    float* out_h      = (float*)d_out;                      // [N,64]
    float* out_reps   = out_h + (size_t)N * 64;             // [128,64]
    float* out_logits = out_reps + (size_t)NGRAPH * 64;     // [128,16]

    int nbE = (E + 255) / 256;
    int nbN = (N + 255) / 256;
    const int GS = 2048;                 // grid-stride blocks (8192 waves)

    hipMemsetAsync(d_ws, 0, zero_bytes, stream);
    deg_kernel<<<nbE, 256, 0, stream>>>(ei, deg, E, N);
    scan1_kernel<<<nbN, 256, 0, stream>>>(deg, bsum, N);
    scan2_kernel<<<1, 256, 0, stream>>>(bsum, boff, nbN);
    scan3_kernel<<<nbN, 256, 0, stream>>>(deg, boff, row_start, dinv, N);
    fill_kernel<<<nbE, 256, 0, stream>>>(ei, row_start, cursor, csr_src, E, N);

    proj_kernel<<<GS, 256, 0, stream>>>(x, W1, dinv, P1, N);
    agg_proj_kernel<<<GS, 256, 0, stream>>>(P1, row_start, csr_src, dinv, b1, W2, P2, N);
    agg_pool_kernel<<<GS, 256, 0, stream>>>(P2, row_start, csr_src, dinv, b2, batch,
                                            out_h, accum, N);
    final_kernel<<<NGRAPH, 64, 0, stream>>>(accum, batch, Wc1, bc1, Wc2, bc2,
                                            out_reps, out_logits, N);
}

// Round 5
// 361.383 us; speedup vs baseline: 1.2637x; 1.1102x over previous
//
#include <hip/hip_runtime.h>
#include <hip/hip_bf16.h>

typedef __hip_bfloat16 bf16;

#define NGRAPH 128

__device__ __forceinline__ float ldP(const bf16* P, int node, int lane) {
    return __bfloat162float(P[(size_t)node * 64 + lane]);
}

// ---------------- degree histogram ----------------
__global__ __launch_bounds__(256) void deg_kernel(const int* __restrict__ ei,
                                                  int* __restrict__ deg, int E, int N) {
    int e = blockIdx.x * 256 + threadIdx.x;
    if (e < E) {
        int d = ei[E + e];                 // dst = ei[1][e]
        d = max(0, min(d, N - 1));
        atomicAdd(&deg[d], 1);
    }
}

// ---------------- scan: per-block sums ----------------
__global__ __launch_bounds__(256) void scan1_kernel(const int* __restrict__ deg,
                                                    int* __restrict__ bsum, int N) {
    __shared__ int tmp[256];
    int i = blockIdx.x * 256 + threadIdx.x;
    tmp[threadIdx.x] = (i < N) ? deg[i] : 0;
    __syncthreads();
    for (int off = 128; off > 0; off >>= 1) {
        if (threadIdx.x < off) tmp[threadIdx.x] += tmp[threadIdx.x + off];
        __syncthreads();
    }
    if (threadIdx.x == 0) bsum[blockIdx.x] = tmp[0];
}

// ---------------- scan: exclusive scan of block sums ----------------
__global__ __launch_bounds__(256) void scan2_kernel(const int* __restrict__ bsum,
                                                    int* __restrict__ boff, int nb) {
    __shared__ int tmp[256];
    __shared__ int carry;
    int tid = threadIdx.x;
    if (tid == 0) carry = 0;
    __syncthreads();
    for (int base = 0; base < nb; base += 256) {
        int i = base + tid;
        int v = (i < nb) ? bsum[i] : 0;
        tmp[tid] = v;
        __syncthreads();
        for (int off = 1; off < 256; off <<= 1) {
            int t = (tid >= off) ? tmp[tid - off] : 0;
            __syncthreads();
            tmp[tid] += t;
            __syncthreads();
        }
        if (i < nb) boff[i] = carry + tmp[tid] - v;
        __syncthreads();
        if (tid == 0) carry += tmp[255];
        __syncthreads();
    }
}

// ---------------- scan: per-element row_start + dinv ----------------
__global__ __launch_bounds__(256) void scan3_kernel(const int* __restrict__ deg,
                                                    const int* __restrict__ boff,
                                                    int* __restrict__ row_start,
                                                    float* __restrict__ dinv, int N) {
    __shared__ int tmp[256];
    int i = blockIdx.x * 256 + threadIdx.x;
    int v = (i < N) ? deg[i] : 0;
    tmp[threadIdx.x] = v;
    __syncthreads();
    for (int off = 1; off < 256; off <<= 1) {
        int t = (threadIdx.x >= off) ? tmp[threadIdx.x - off] : 0;
        __syncthreads();
        tmp[threadIdx.x] += t;
        __syncthreads();
    }
    if (i < N) {
        int excl = tmp[threadIdx.x] - v;
        int rs = boff[blockIdx.x] + excl;
        row_start[i] = rs;
        if (i == N - 1) row_start[N] = rs + v;
        dinv[i] = rsqrtf((float)(v + 1));   // +1 self loop
    }
}

// ---------------- CSR fill (dst-sorted src list) ----------------
__global__ __launch_bounds__(256) void fill_kernel(const int* __restrict__ ei,
                                                   const int* __restrict__ row_start,
                                                   int* __restrict__ cursor,
                                                   int* __restrict__ csr_src, int E, int N) {
    int e = blockIdx.x * 256 + threadIdx.x;
    if (e < E) {
        int s = ei[e];     s = max(0, min(s, N - 1));
        int d = ei[E + e]; d = max(0, min(d, N - 1));
        int pos = row_start[d] + atomicAdd(&cursor[d], 1);
        if (pos >= 0 && pos < E) csr_src[pos] = s;
    }
}

// ---------------- P1 = (x @ W1) * dinv  (wave-per-node, grid-stride) ----------------
__global__ __launch_bounds__(256) void proj_kernel(const float* __restrict__ A,
                                                   const float* __restrict__ W,
                                                   const float* __restrict__ dinv,
                                                   bf16* __restrict__ P, int N) {
    __shared__ float Wl[4096];
    for (int i = threadIdx.x; i < 4096; i += 256) Wl[i] = W[i];
    __syncthreads();
    int lane = threadIdx.x & 63;
    int wid = (blockIdx.x * 256 + threadIdx.x) >> 6;
    int nwaves = (gridDim.x * 256) >> 6;
    for (int node = wid; node < N; node += nwaves) {
        float a = A[(size_t)node * 64 + lane];
        float acc = 0.f;
#pragma unroll
        for (int k = 0; k < 64; ++k) acc += __shfl(a, k) * Wl[k * 64 + lane];
        P[(size_t)node * 64 + lane] = __float2bfloat16(acc * dinv[node]);
    }
}

// ---- ILP-4 neighbor gather: returns sum over P[src] rows for this node ----
__device__ __forceinline__ float gather_sum(const bf16* __restrict__ P,
                                            const int* __restrict__ csr_src,
                                            int beg, int end, int lane) {
    float a0 = 0.f, a1 = 0.f, a2 = 0.f, a3 = 0.f;
    for (int i = beg; i < end; i += 64) {
        int e = i + lane;
        int s = (e < end) ? csr_src[e] : 0;
        int m = min(end - i, 64);
        int j = 0;
        for (; j + 4 <= m; j += 4) {
            int s0 = __builtin_amdgcn_readlane(s, j);
            int s1 = __builtin_amdgcn_readlane(s, j + 1);
            int s2 = __builtin_amdgcn_readlane(s, j + 2);
            int s3 = __builtin_amdgcn_readlane(s, j + 3);
            float v0 = ldP(P, s0, lane);
            float v1 = ldP(P, s1, lane);
            float v2 = ldP(P, s2, lane);
            float v3 = ldP(P, s3, lane);
            a0 += v0; a1 += v1; a2 += v2; a3 += v3;
        }
        for (; j < m; ++j) {
            int sj = __builtin_amdgcn_readlane(s, j);
            a0 += ldP(P, sj, lane);
        }
    }
    return (a0 + a1) + (a2 + a3);
}

// ---- layer1 aggregate + fused layer2 projection ----
__global__ __launch_bounds__(256) void agg_proj_kernel(const bf16* __restrict__ P1,
                                                       const int* __restrict__ row_start,
                                                       const int* __restrict__ csr_src,
                                                       const float* __restrict__ dinv,
                                                       const float* __restrict__ b1,
                                                       const float* __restrict__ W2,
                                                       bf16* __restrict__ P2, int N) {
    __shared__ float Wl[4096];
    for (int i = threadIdx.x; i < 4096; i += 256) Wl[i] = W2[i];
    __syncthreads();
    int lane = threadIdx.x & 63;
    int wid = (blockIdx.x * 256 + threadIdx.x) >> 6;
    int nwaves = (gridDim.x * 256) >> 6;
    for (int node = wid; node < N; node += nwaves) {
        float acc = ldP(P1, node, lane)
                  + gather_sum(P1, csr_src, row_start[node], row_start[node + 1], lane);
        float h1 = fmaxf(acc * dinv[node] + b1[lane], 0.f);
        float acc2 = 0.f;
#pragma unroll
        for (int k = 0; k < 64; ++k) acc2 += __shfl(h1, k) * Wl[k * 64 + lane];
        P2[(size_t)node * 64 + lane] = __float2bfloat16(acc2 * dinv[node]);
    }
}

// ---- layer2 aggregate + fused mean-pool accumulation ----
__global__ __launch_bounds__(256) void agg_pool_kernel(const bf16* __restrict__ P2,
                                                       const int* __restrict__ row_start,
                                                       const int* __restrict__ csr_src,
                                                       const float* __restrict__ dinv,
                                                       const float* __restrict__ b2,
                                                       const int* __restrict__ batch,
                                                       float* __restrict__ out_h,
                                                       float* __restrict__ accum, int N) {
    int lane = threadIdx.x & 63;
    int wid = (blockIdx.x * 256 + threadIdx.x) >> 6;
    int nwaves = (gridDim.x * 256) >> 6;
    for (int node = wid; node < N; node += nwaves) {
        float acc = ldP(P2, node, lane)
                  + gather_sum(P2, csr_src, row_start[node], row_start[node + 1], lane);
        float h2 = acc * dinv[node] + b2[lane];
        out_h[(size_t)node * 64 + lane] = h2;
        int g = batch[node];
        g = max(0, min(g, NGRAPH - 1));
        atomicAdd(&accum[g * 64 + lane], h2);
    }
}

// ---------------- finalize pool (divide by count) + classifier head ----------------
__device__ __forceinline__ int lower_bound_dev(const int* a, int n, int key) {
    int lo = 0, hi = n;
    while (lo < hi) {
        int mid = (lo + hi) >> 1;
        if (a[mid] < key) lo = mid + 1; else hi = mid;
    }
    return lo;
}

__global__ __launch_bounds__(64) void final_kernel(const float* __restrict__ accum,
                                                   const int* __restrict__ batch,
                                                   const float* __restrict__ Wc1,
                                                   const float* __restrict__ bc1,
                                                   const float* __restrict__ Wc2,
                                                   const float* __restrict__ bc2,
                                                   float* __restrict__ out_reps,
                                                   float* __restrict__ out_logits, int N) {
    __shared__ float rep[64];
    __shared__ float t[64];
    int g = blockIdx.x;
    int f = threadIdx.x;
    int lo = lower_bound_dev(batch, N, g);
    int hi = lower_bound_dev(batch, N, g + 1);
    float cnt = (float)(hi - lo);
    float r = accum[g * 64 + f] / fmaxf(cnt, 1.f);
    out_reps[g * 64 + f] = r;
    rep[f] = r;
    __syncthreads();
    float acc = bc1[f];
#pragma unroll
    for (int k = 0; k < 64; ++k) acc += rep[k] * Wc1[k * 64 + f];
    t[f] = fmaxf(acc, 0.f);
    __syncthreads();
    if (f < 16) {
        float a2 = bc2[f];
#pragma unroll
        for (int k = 0; k < 64; ++k) a2 += t[k] * Wc2[k * 16 + f];
        out_logits[g * 16 + f] = a2;
    }
}

extern "C" void kernel_launch(void* const* d_in, const int* in_sizes, int n_in,
                              void* d_out, int out_size, void* d_ws, size_t ws_size,
                              hipStream_t stream) {
    const float* x    = (const float*)d_in[0];
    const int*   ei   = (const int*)d_in[1];
    const int*   batch= (const int*)d_in[2];
    const float* W1   = (const float*)d_in[3];
    const float* b1   = (const float*)d_in[4];
    const float* W2   = (const float*)d_in[5];
    const float* b2   = (const float*)d_in[6];
    const float* Wc1  = (const float*)d_in[7];
    const float* bc1  = (const float*)d_in[8];
    const float* Wc2  = (const float*)d_in[9];
    const float* bc2  = (const float*)d_in[10];

    const int N = in_sizes[2];          // 50000
    const int E = in_sizes[1] / 2;      // 800000

    // ---- workspace layout (~7.3 MB) ----
    char* ws = (char*)d_ws;
    size_t off = 0;
    auto alloc = [&](size_t bytes) { void* p = ws + off; off += (bytes + 255) & ~(size_t)255; return p; };
    int*   deg       = (int*)  alloc((size_t)N * 4);
    int*   cursor    = (int*)  alloc((size_t)N * 4);
    float* accum     = (float*)alloc((size_t)NGRAPH * 64 * 4);
    size_t zero_bytes = off;                       // deg + cursor + accum start at 0
    float* dinv      = (float*)alloc((size_t)N * 4);
    int*   row_start = (int*)  alloc((size_t)(N + 1) * 4);
    int*   bsum      = (int*)  alloc(1024);
    int*   boff      = (int*)  alloc(1024);
    int*   csr_src   = (int*)  alloc((size_t)E * 4);
    bf16*  P1        = (bf16*) alloc((size_t)N * 64 * 2);
    bf16*  P2        = (bf16*) alloc((size_t)N * 64 * 2);
    (void)ws_size; (void)n_in; (void)out_size;

    float* out_h      = (float*)d_out;                      // [N,64]
    float* out_reps   = out_h + (size_t)N * 64;             // [128,64]
    float* out_logits = out_reps + (size_t)NGRAPH * 64;     // [128,16]

    int nbE = (E + 255) / 256;
    int nbN = (N + 255) / 256;
    const int GS = 2048;                 // grid-stride blocks (8192 waves)

    hipMemsetAsync(d_ws, 0, zero_bytes, stream);
    deg_kernel<<<nbE, 256, 0, stream>>>(ei, deg, E, N);
    scan1_kernel<<<nbN, 256, 0, stream>>>(deg, bsum, N);
    scan2_kernel<<<1, 256, 0, stream>>>(bsum, boff, nbN);
    scan3_kernel<<<nbN, 256, 0, stream>>>(deg, boff, row_start, dinv, N);
    fill_kernel<<<nbE, 256, 0, stream>>>(ei, row_start, cursor, csr_src, E, N);

    proj_kernel<<<GS, 256, 0, stream>>>(x, W1, dinv, P1, N);
    agg_proj_kernel<<<GS, 256, 0, stream>>>(P1, row_start, csr_src, dinv, b1, W2, P2, N);
    agg_pool_kernel<<<GS, 256, 0, stream>>>(P2, row_start, csr_src, dinv, b2, batch,
                                            out_h, accum, N);
    final_kernel<<<NGRAPH, 64, 0, stream>>>(accum, batch, Wc1, bc1, Wc2, bc2,
                                            out_reps, out_logits, N);
}